// Round 1
// baseline (4746.238 us; speedup 1.0000x reference)
//
#include <hip/hip_runtime.h>
#include <hip/hip_bf16.h>

#define DIMC 384
#define NHEADS 12
#define NTOK 144
#define TABLEN 529
#define BWIN 512
#define NWIN 16
#define CPBH 512

using bf16 = __hip_bfloat16;

// ---------------- kernel 1: CPB-MLP table (529 x 12) + per-head logit scales ----------------
__global__ void cpb_kernel(const float* __restrict__ rct,
                           const float* __restrict__ w1,
                           const float* __restrict__ b1,
                           const float* __restrict__ w2,
                           const float* __restrict__ logit_scale,
                           float* __restrict__ bias_tab,
                           float* __restrict__ scalev) {
  int t = blockIdx.x * blockDim.x + threadIdx.x;
  if (t < NHEADS) scalev[t] = __expf(fminf(logit_scale[t], 4.60517018598809f)); // ln(100)
  if (t >= TABLEN * NHEADS) return;
  int i = t / NHEADS, h = t % NHEADS;
  float c0 = rct[2 * i], c1 = rct[2 * i + 1];
  const float* w2h = w2 + (size_t)h * CPBH;
  float acc = 0.f;
  for (int k = 0; k < CPBH; ++k) {
    float hv = fmaxf(0.f, fmaf(c0, w1[2 * k], fmaf(c1, w1[2 * k + 1], b1[k])));
    acc = fmaf(hv, w2h[k], acc);
  }
  bias_tab[i * NHEADS + h] = 16.f / (1.f + __expf(-acc));
}

// ---------------- kernel 1b: pre-gather rpb_full[h][r][m] = bias_tab[idx[r][m]][h] ----------------
__global__ void rpb_gather_kernel(const int* __restrict__ rpi,
                                  const float* __restrict__ bias_tab,
                                  float* __restrict__ rpb_full) {
  int e = blockIdx.x * blockDim.x + threadIdx.x;
  if (e >= NHEADS * NTOK * NTOK) return;
  int h = e / (NTOK * NTOK);
  int rm = e % (NTOK * NTOK);
  rpb_full[e] = bias_tab[rpi[rm] * NHEADS + h];
}

// ---------------- kernel 2: fused QKV + cosine attention per (window b, head h) ----------------
// block = 192 threads (3 waves); threads 0..143 each own one query row.
__global__ __launch_bounds__(192) void attn_kernel(
    const float* __restrict__ x,
    const float* __restrict__ qkv_w,
    const float* __restrict__ q_bias,
    const float* __restrict__ k_bias,
    const float* __restrict__ v_bias,
    const float* __restrict__ mask,
    const float* __restrict__ rpb_full,
    const float* __restrict__ scalev,
    bf16* __restrict__ ctx) {
  // pad to 36 floats/row: float4-aligned rows, conflict-tolerable strides
  __shared__ float qs[NTOK][36];
  __shared__ float ks[NTOK][36];
  __shared__ float vs[NTOK][36];

  int blk = blockIdx.x;
  int b = blk / NHEADS, h = blk % NHEADS;
  int tid = threadIdx.x;
  float scale_h = scalev[h];

  if (tid < NTOK) {
    // ---- phase 1: this thread computes q/k/v row `tid` for head h (384-dot each col) ----
    const float* xrow = x + ((size_t)b * NTOK + tid) * DIMC;
    float ssq = 0.f, ssk = 0.f;
    for (int jb = 0; jb < 4; ++jb) {
      float aq[8], ak[8], av[8];
#pragma unroll
      for (int j = 0; j < 8; ++j) { aq[j] = 0.f; ak[j] = 0.f; av[j] = 0.f; }
      const float* wq = qkv_w + (size_t)(h * 32 + jb * 8) * DIMC;
      const float* wk = wq + (size_t)384 * DIMC;
      const float* wv = wk + (size_t)384 * DIMC;
      for (int c = 0; c < DIMC; c += 4) {
        float4 xv = *(const float4*)(xrow + c);
#pragma unroll
        for (int j = 0; j < 8; ++j) {
          float4 wqv = *(const float4*)(wq + j * DIMC + c);  // uniform -> s_load
          float4 wkv = *(const float4*)(wk + j * DIMC + c);
          float4 wvv = *(const float4*)(wv + j * DIMC + c);
          aq[j] = fmaf(xv.x, wqv.x, aq[j]); aq[j] = fmaf(xv.y, wqv.y, aq[j]);
          aq[j] = fmaf(xv.z, wqv.z, aq[j]); aq[j] = fmaf(xv.w, wqv.w, aq[j]);
          ak[j] = fmaf(xv.x, wkv.x, ak[j]); ak[j] = fmaf(xv.y, wkv.y, ak[j]);
          ak[j] = fmaf(xv.z, wkv.z, ak[j]); ak[j] = fmaf(xv.w, wkv.w, ak[j]);
          av[j] = fmaf(xv.x, wvv.x, av[j]); av[j] = fmaf(xv.y, wvv.y, av[j]);
          av[j] = fmaf(xv.z, wvv.z, av[j]); av[j] = fmaf(xv.w, wvv.w, av[j]);
        }
      }
#pragma unroll
      for (int j = 0; j < 8; ++j) {
        int col = h * 32 + jb * 8 + j;
        float qv = aq[j] + q_bias[col];
        float kv = ak[j] + k_bias[col];
        float vv = av[j] + v_bias[col];
        ssq = fmaf(qv, qv, ssq);
        ssk = fmaf(kv, kv, ssk);
        qs[tid][jb * 8 + j] = qv;
        ks[tid][jb * 8 + j] = kv;
        vs[tid][jb * 8 + j] = vv;
      }
    }
    // cosine-normalize; fold logit scale into q
    float invq = scale_h / sqrtf(ssq);
    float invk = 1.f / sqrtf(ssk);
#pragma unroll
    for (int j = 0; j < 32; ++j) { qs[tid][j] *= invq; ks[tid][j] *= invk; }
  }
  __syncthreads();

  if (tid < NTOK) {
    // ---- phase 2: row `tid` online softmax (pass A) + recompute & PV (pass B) ----
    float qr[32];
#pragma unroll
    for (int j = 0; j < 32; ++j) qr[j] = qs[tid][j];
    const float* rpbrow = rpb_full + ((size_t)h * NTOK + tid) * NTOK;
    const float* maskrow = mask + ((size_t)(b % NWIN) * NTOK + tid) * NTOK;

    float mrun = -1e30f, lrun = 0.f;
    for (int m = 0; m < NTOK; ++m) {
      const float* krow = ks[m];
      float s0 = 0.f, s1 = 0.f, s2 = 0.f, s3 = 0.f;
#pragma unroll
      for (int j = 0; j < 32; j += 4) {
        s0 = fmaf(qr[j + 0], krow[j + 0], s0);
        s1 = fmaf(qr[j + 1], krow[j + 1], s1);
        s2 = fmaf(qr[j + 2], krow[j + 2], s2);
        s3 = fmaf(qr[j + 3], krow[j + 3], s3);
      }
      float s = (s0 + s1) + (s2 + s3) + rpbrow[m] + maskrow[m];
      float nm = fmaxf(mrun, s);
      lrun = fmaf(lrun, __expf(mrun - nm), __expf(s - nm));
      mrun = nm;
    }

    float o[32];
#pragma unroll
    for (int j = 0; j < 32; ++j) o[j] = 0.f;
    for (int m = 0; m < NTOK; ++m) {
      const float* krow = ks[m];
      float s0 = 0.f, s1 = 0.f, s2 = 0.f, s3 = 0.f;
#pragma unroll
      for (int j = 0; j < 32; j += 4) {
        s0 = fmaf(qr[j + 0], krow[j + 0], s0);
        s1 = fmaf(qr[j + 1], krow[j + 1], s1);
        s2 = fmaf(qr[j + 2], krow[j + 2], s2);
        s3 = fmaf(qr[j + 3], krow[j + 3], s3);
      }
      float s = (s0 + s1) + (s2 + s3) + rpbrow[m] + maskrow[m];
      float p = __expf(s - mrun);
      const float* vrow = vs[m];
#pragma unroll
      for (int j = 0; j < 32; ++j) o[j] = fmaf(p, vrow[j], o[j]);
    }
    float rinv = 1.f / lrun;
    bf16* crow = ctx + ((size_t)b * NTOK + tid) * DIMC + h * 32;
#pragma unroll
    for (int j = 0; j < 32; ++j) crow[j] = __float2bfloat16(o[j] * rinv);
  }
}

// ---------------- kernel 3: output projection GEMM (73728 x 384) @ (384 x 384)^T + bias ----------------
__global__ __launch_bounds__(256) void proj_kernel(
    const bf16* __restrict__ ctx,
    const float* __restrict__ proj_w,
    const float* __restrict__ proj_b,
    float* __restrict__ out) {
  __shared__ float As[64][36];
  __shared__ float Bs[64][36];
  int tid = threadIdx.x;
  int bn0 = blockIdx.y * 64;  // row block of flattened (B*N)
  int n0 = blockIdx.x * 64;   // col block of DIMC
  int tx = tid & 15, ty = tid >> 4;
  float acc[4][4];
#pragma unroll
  for (int i = 0; i < 4; ++i)
#pragma unroll
    for (int j = 0; j < 4; ++j) acc[i][j] = 0.f;

  for (int k0 = 0; k0 < DIMC; k0 += 32) {
    {  // stage A tile: 64 rows x 32 k of bf16 ctx
      int row = tid >> 2;
      int kk = (tid & 3) * 8;
      uint4 u = *(const uint4*)(ctx + ((size_t)(bn0 + row)) * DIMC + k0 + kk);
      float4 lo, hi2;
      lo.x = __uint_as_float(u.x << 16); lo.y = __uint_as_float(u.x & 0xffff0000u);
      lo.z = __uint_as_float(u.y << 16); lo.w = __uint_as_float(u.y & 0xffff0000u);
      hi2.x = __uint_as_float(u.z << 16); hi2.y = __uint_as_float(u.z & 0xffff0000u);
      hi2.z = __uint_as_float(u.w << 16); hi2.w = __uint_as_float(u.w & 0xffff0000u);
      *(float4*)&As[row][kk] = lo;
      *(float4*)&As[row][kk + 4] = hi2;
    }
    {  // stage B tile: 64 rows x 32 k of proj_w (f32)
      int row = tid >> 3;
      int kk = (tid & 7) * 4;
#pragma unroll
      for (int rr = 0; rr < 2; ++rr) {
        float4 w = *(const float4*)(proj_w + (size_t)(n0 + row + rr * 32) * DIMC + k0 + kk);
        *(float4*)&Bs[row + rr * 32][kk] = w;
      }
    }
    __syncthreads();
#pragma unroll
    for (int kk = 0; kk < 32; kk += 4) {
      float4 a[4], bb[4];
#pragma unroll
      for (int i = 0; i < 4; ++i) a[i] = *(const float4*)&As[ty * 4 + i][kk];
#pragma unroll
      for (int j = 0; j < 4; ++j) bb[j] = *(const float4*)&Bs[tx * 4 + j][kk];
#pragma unroll
      for (int i = 0; i < 4; ++i)
#pragma unroll
        for (int j = 0; j < 4; ++j) {
          acc[i][j] = fmaf(a[i].x, bb[j].x, acc[i][j]);
          acc[i][j] = fmaf(a[i].y, bb[j].y, acc[i][j]);
          acc[i][j] = fmaf(a[i].z, bb[j].z, acc[i][j]);
          acc[i][j] = fmaf(a[i].w, bb[j].w, acc[i][j]);
        }
    }
    __syncthreads();
  }
#pragma unroll
  for (int i = 0; i < 4; ++i) {
    size_t r = (size_t)(bn0 + ty * 4 + i);
    int cc = n0 + tx * 4;
    float4 ov;
    ov.x = acc[i][0] + proj_b[cc + 0];
    ov.y = acc[i][1] + proj_b[cc + 1];
    ov.z = acc[i][2] + proj_b[cc + 2];
    ov.w = acc[i][3] + proj_b[cc + 3];
    *(float4*)&out[r * DIMC + cc] = ov;
  }
}

extern "C" void kernel_launch(void* const* d_in, const int* in_sizes, int n_in,
                              void* d_out, int out_size, void* d_ws, size_t ws_size,
                              hipStream_t stream) {
  const float* x = (const float*)d_in[0];
  const float* rct = (const float*)d_in[1];
  const int* rpi = (const int*)d_in[2];
  const float* mask = (const float*)d_in[3];
  const float* qkv_w = (const float*)d_in[4];
  const float* q_bias = (const float*)d_in[5];
  const float* k_bias = (const float*)d_in[6];
  const float* v_bias = (const float*)d_in[7];
  const float* logit_scale = (const float*)d_in[8];
  const float* cpb_w1 = (const float*)d_in[9];
  const float* cpb_b1 = (const float*)d_in[10];
  const float* cpb_w2 = (const float*)d_in[11];
  const float* proj_w = (const float*)d_in[12];
  const float* proj_b = (const float*)d_in[13];
  float* out = (float*)d_out;

  char* ws = (char*)d_ws;
  float* scalev = (float*)ws;              // 64 floats reserved
  float* bias_tab = scalev + 64;           // 529*12
  float* rpb_full = bias_tab + TABLEN * NHEADS;  // 12*144*144
  size_t head_bytes = (size_t)(64 + TABLEN * NHEADS + NHEADS * NTOK * NTOK) * 4;
  head_bytes = (head_bytes + 255) & ~(size_t)255;
  bf16* ctx = (bf16*)(ws + head_bytes);    // 512*144*384 bf16 = 56.6 MB

  cpb_kernel<<<(TABLEN * NHEADS + 255) / 256, 256, 0, stream>>>(
      rct, cpb_w1, cpb_b1, cpb_w2, logit_scale, bias_tab, scalev);
  rpb_gather_kernel<<<(NHEADS * NTOK * NTOK + 255) / 256, 256, 0, stream>>>(
      rpi, bias_tab, rpb_full);
  attn_kernel<<<BWIN * NHEADS, 192, 0, stream>>>(
      x, qkv_w, q_bias, k_bias, v_bias, mask, rpb_full, scalev, ctx);
  proj_kernel<<<dim3(DIMC / 64, (BWIN * NTOK) / 64), 256, 0, stream>>>(
      ctx, proj_w, proj_b, out);
}

// Round 2
// 398.174 us; speedup vs baseline: 11.9200x; 11.9200x over previous
//
#include <hip/hip_runtime.h>

#define DIMC 384
#define NHEADS 12
#define NTOK 144
#define TABLEN 529
#define BWIN 512
#define NWIN 16
#define CPBH 512

typedef unsigned short u16;
typedef unsigned int u32;
typedef __attribute__((ext_vector_type(8))) short short8;
typedef __attribute__((ext_vector_type(4))) float f32x4;

#define MFMA(a, b, c) __builtin_amdgcn_mfma_f32_16x16x32_bf16((a), (b), (c), 0, 0, 0)

__device__ __forceinline__ u16 f2bf(float f) {
  union { float f; u32 u; } v; v.f = f;
  u32 r = v.u + 0x7fffu + ((v.u >> 16) & 1u);
  return (u16)(r >> 16);
}
__device__ __forceinline__ u32 pk2(float a, float b) {
  return (u32)f2bf(a) | ((u32)f2bf(b) << 16);
}

// ---------------- f32 -> bf16 bulk convert (8 elems/thread) ----------------
__global__ __launch_bounds__(256) void cvt_bf16(const float* __restrict__ in,
                                                u16* __restrict__ out, int n8) {
  int i = blockIdx.x * 256 + threadIdx.x;
  if (i >= n8) return;
  const float4* p = (const float4*)(in + (size_t)i * 8);
  float4 a = p[0], b = p[1];
  uint4 r;
  r.x = pk2(a.x, a.y); r.y = pk2(a.z, a.w);
  r.z = pk2(b.x, b.y); r.w = pk2(b.z, b.w);
  *(uint4*)(out + (size_t)i * 8) = r;
}

// ---------------- CPB-MLP table (529 x 12, sigmoid applied) + per-head scales ----------------
__global__ void cpb_kernel(const float* __restrict__ rct,
                           const float* __restrict__ w1,
                           const float* __restrict__ b1,
                           const float* __restrict__ w2,
                           const float* __restrict__ logit_scale,
                           float* __restrict__ bias_tab,
                           float* __restrict__ scalev) {
  int t = blockIdx.x * blockDim.x + threadIdx.x;
  if (t < NHEADS) scalev[t] = __expf(fminf(logit_scale[t], 4.60517018598809f));
  if (t >= TABLEN * NHEADS) return;
  int i = t / NHEADS, h = t % NHEADS;
  float c0 = rct[2 * i], c1 = rct[2 * i + 1];
  const float* w2h = w2 + (size_t)h * CPBH;
  float acc = 0.f;
  for (int k = 0; k < CPBH; ++k) {
    float hv = fmaxf(0.f, fmaf(c0, w1[2 * k], fmaf(c1, w1[2 * k + 1], b1[k])));
    acc = fmaf(hv, w2h[k], acc);
  }
  bias_tab[i * NHEADS + h] = 16.f / (1.f + __expf(-acc));
}

// ---------------- combined bias: cb[w][h][n][m] = rpb + mask (fp32) ----------------
__global__ __launch_bounds__(256) void cbias_kernel(const int* __restrict__ rpi,
                                                    const float* __restrict__ bias_tab,
                                                    const float* __restrict__ mask,
                                                    float* __restrict__ cb) {
  int e = blockIdx.x * 256 + threadIdx.x;
  if (e >= NWIN * NHEADS * NTOK * NTOK) return;
  int m = e % NTOK;
  int t = e / NTOK;
  int n = t % NTOK; t /= NTOK;
  int h = t % NHEADS;
  int w = t / NHEADS;
  cb[e] = bias_tab[rpi[n * NTOK + m] * NHEADS + h] + mask[(w * NTOK + n) * NTOK + m];
}

// ---------------- fused QKV-projection + cosine attention per (window b, head h) ----------------
// 192 threads = 3 waves; wave w owns query rows [48w, 48w+48).
__global__ __launch_bounds__(192) void attn_fused(
    const u16* __restrict__ xb, const u16* __restrict__ wb,
    const float* __restrict__ q_bias, const float* __restrict__ k_bias,
    const float* __restrict__ v_bias, const float* __restrict__ cb,
    const float* __restrict__ scalev, u16* __restrict__ ctx) {
  __shared__ u16 smem[22656];  // 45312 B
  u16* qn = smem;               // [144][40] normalized q (scale folded)
  u16* kn = smem + 5760;        // [144][40] normalized k
  u16* vT = smem + 11520;       // [32][168] v transposed, m-padded to 160+
  u16* Pc = smem + 16896;       // [144][40] P chunk (32 m-cols per wave slice)
  u16* xs = smem;               // QKV-phase alias: [144][40] x chunk
  u16* wsm = smem + 5760;       // QKV-phase alias: [96][40] W chunk

  int bid = blockIdx.x;
  int b = bid / NHEADS, h = bid - b * NHEADS;
  int tid = threadIdx.x;
  int lane = tid & 63, wv = tid >> 6;
  int g = lane >> 4, c = lane & 15;
  int rbase = wv * 48;

  // ---- phase 1: QKV projection via MFMA, K chunked by 32 ----
  f32x4 acc[3][6];
#pragma unroll
  for (int i = 0; i < 3; ++i)
#pragma unroll
    for (int j = 0; j < 6; ++j) acc[i][j] = (f32x4){0.f, 0.f, 0.f, 0.f};

  int r4 = tid >> 2, s8 = (tid & 3) * 8;
  for (int t = 0; t < 12; ++t) {
    int k0 = t * 32;
#pragma unroll
    for (int p = 0; p < 3; ++p) {
      int row = p * 48 + r4;
      uint4 v = *(const uint4*)(xb + ((size_t)b * NTOK + row) * DIMC + k0 + s8);
      *(uint4*)(xs + row * 40 + s8) = v;
    }
#pragma unroll
    for (int p = 0; p < 2; ++p) {
      int row = p * 48 + r4;
      int sec = row >> 5, jj = row & 31;
      int wrow = sec * DIMC + h * 32 + jj;
      uint4 v = *(const uint4*)(wb + (size_t)wrow * DIMC + k0 + s8);
      *(uint4*)(wsm + row * 40 + s8) = v;
    }
    __syncthreads();
    short8 ax[3];
#pragma unroll
    for (int nt = 0; nt < 3; ++nt)
      ax[nt] = *(const short8*)(xs + (rbase + nt * 16 + c) * 40 + g * 8);
#pragma unroll
    for (int ni = 0; ni < 6; ++ni) {
      short8 bw = *(const short8*)(wsm + (ni * 16 + c) * 40 + g * 8);
#pragma unroll
      for (int nt = 0; nt < 3; ++nt) acc[nt][ni] = MFMA(ax[nt], bw, acc[nt][ni]);
    }
    __syncthreads();
  }

  // ---- phase 2: bias + cosine-normalize in-register, write qn/kn/vT ----
  float sch = scalev[h];
  float qb0 = q_bias[h * 32 + c], qb1 = q_bias[h * 32 + 16 + c];
  float kb0 = k_bias[h * 32 + c], kb1 = k_bias[h * 32 + 16 + c];
  float vb0 = v_bias[h * 32 + c], vb1 = v_bias[h * 32 + 16 + c];
#pragma unroll
  for (int nt = 0; nt < 3; ++nt) {
#pragma unroll
    for (int r = 0; r < 4; ++r) {
      int row = rbase + nt * 16 + g * 4 + r;
      float q0 = acc[nt][0][r] + qb0, q1 = acc[nt][1][r] + qb1;
      float ssq = q0 * q0 + q1 * q1;
      ssq += __shfl_xor(ssq, 1); ssq += __shfl_xor(ssq, 2);
      ssq += __shfl_xor(ssq, 4); ssq += __shfl_xor(ssq, 8);
      float siq = sch / sqrtf(ssq);
      qn[row * 40 + c] = f2bf(q0 * siq);
      qn[row * 40 + 16 + c] = f2bf(q1 * siq);
      float k0v = acc[nt][2][r] + kb0, k1v = acc[nt][3][r] + kb1;
      float ssk = k0v * k0v + k1v * k1v;
      ssk += __shfl_xor(ssk, 1); ssk += __shfl_xor(ssk, 2);
      ssk += __shfl_xor(ssk, 4); ssk += __shfl_xor(ssk, 8);
      float sik = 1.f / sqrtf(ssk);
      kn[row * 40 + c] = f2bf(k0v * sik);
      kn[row * 40 + 16 + c] = f2bf(k1v * sik);
      float v0 = acc[nt][4][r] + vb0, v1 = acc[nt][5][r] + vb1;
      vT[c * 168 + row] = f2bf(v0);
      vT[(16 + c) * 168 + row] = f2bf(v1);
    }
  }
  if (tid < 32) {  // zero the m-pad (144..167) so padded-K MFMA adds 0
    uint4 z4 = {0u, 0u, 0u, 0u};
    *(uint4*)(vT + tid * 168 + 144) = z4;
    *(uint4*)(vT + tid * 168 + 152) = z4;
    *(uint4*)(vT + tid * 168 + 160) = z4;
  }
  __syncthreads();

  // ---- phase 3: S = qn . kn^T (16x16x32 MFMA, K=d=32) ----
  short8 aq[3];
#pragma unroll
  for (int nt = 0; nt < 3; ++nt)
    aq[nt] = *(const short8*)(qn + (rbase + nt * 16 + c) * 40 + g * 8);
  f32x4 S[3][9];
#pragma unroll
  for (int mt = 0; mt < 9; ++mt) {
    short8 bk = *(const short8*)(kn + (mt * 16 + c) * 40 + g * 8);
#pragma unroll
    for (int nt = 0; nt < 3; ++nt) {
      f32x4 z = (f32x4){0.f, 0.f, 0.f, 0.f};
      S[nt][mt] = MFMA(aq[nt], bk, z);
    }
  }

  // ---- phase 4: + (rpb + mask), row softmax (folded 1/sum into P) ----
  const float* cbh = cb + (((size_t)(b & (NWIN - 1)) * NHEADS + h) * NTOK) * NTOK;
#pragma unroll
  for (int nt = 0; nt < 3; ++nt) {
#pragma unroll
    for (int r = 0; r < 4; ++r) {
      int row = rbase + nt * 16 + g * 4 + r;
      const float* crow = cbh + (size_t)row * NTOK + c;
      float sv[9];
      float mx = -1e30f;
#pragma unroll
      for (int mt = 0; mt < 9; ++mt) {
        float s = S[nt][mt][r] + crow[mt * 16];
        sv[mt] = s;
        mx = fmaxf(mx, s);
      }
      mx = fmaxf(mx, __shfl_xor(mx, 1)); mx = fmaxf(mx, __shfl_xor(mx, 2));
      mx = fmaxf(mx, __shfl_xor(mx, 4)); mx = fmaxf(mx, __shfl_xor(mx, 8));
      float sum = 0.f;
#pragma unroll
      for (int mt = 0; mt < 9; ++mt) {
        float p = __expf(sv[mt] - mx);
        sv[mt] = p;
        sum += p;
      }
      sum += __shfl_xor(sum, 1); sum += __shfl_xor(sum, 2);
      sum += __shfl_xor(sum, 4); sum += __shfl_xor(sum, 8);
      float rinv = 1.f / sum;
#pragma unroll
      for (int mt = 0; mt < 9; ++mt) S[nt][mt][r] = sv[mt] * rinv;
    }
  }

  // ---- phase 5: PV, K(m) chunked by 32 via per-wave P bounce in LDS ----
  f32x4 po[3][2];
#pragma unroll
  for (int i = 0; i < 3; ++i)
#pragma unroll
    for (int j = 0; j < 2; ++j) po[i][j] = (f32x4){0.f, 0.f, 0.f, 0.f};
  for (int ck = 0; ck < 5; ++ck) {
#pragma unroll
    for (int nt = 0; nt < 3; ++nt)
#pragma unroll
      for (int mt2 = 0; mt2 < 2; ++mt2) {
        int MT = ck * 2 + mt2;
#pragma unroll
        for (int r = 0; r < 4; ++r) {
          int row = rbase + nt * 16 + g * 4 + r;
          float p = (MT < 9) ? S[nt][MT][r] : 0.f;
          Pc[row * 40 + mt2 * 16 + c] = f2bf(p);
        }
      }
#pragma unroll
    for (int nt = 0; nt < 3; ++nt) {
      short8 pa = *(const short8*)(Pc + (rbase + nt * 16 + c) * 40 + g * 8);
#pragma unroll
      for (int dt = 0; dt < 2; ++dt) {
        short8 vb = *(const short8*)(vT + (dt * 16 + c) * 168 + ck * 32 + g * 8);
        po[nt][dt] = MFMA(pa, vb, po[nt][dt]);
      }
    }
  }

  // ---- epilogue: ctx[b*144+n][h*32+d] bf16 ----
#pragma unroll
  for (int nt = 0; nt < 3; ++nt)
#pragma unroll
    for (int dt = 0; dt < 2; ++dt)
#pragma unroll
      for (int r = 0; r < 4; ++r) {
        int n = rbase + nt * 16 + g * 4 + r;
        ctx[((size_t)b * NTOK + n) * DIMC + h * 32 + dt * 16 + c] = f2bf(po[nt][dt][r]);
      }
}

// ---------------- output projection: (73728 x 384) @ (384 x 384)^T + bias, bf16 MFMA ----------------
__global__ __launch_bounds__(256) void proj_gemm(const u16* __restrict__ ctx,
                                                 const u16* __restrict__ pwb,
                                                 const float* __restrict__ proj_b,
                                                 float* __restrict__ out) {
  __shared__ u16 As[128 * 64];
  __shared__ u16 Bs[128 * 64];
  int bid = blockIdx.x;
  int nblk = bid % 3, mblk = bid / 3;
  size_t gm0 = (size_t)mblk * 128;
  int gn0 = nblk * 128;
  int tid = threadIdx.x, lane = tid & 63, wid = tid >> 6;
  int wr = wid >> 1, wc = wid & 1, g = lane >> 4, c = lane & 15;
  f32x4 acc[4][4];
#pragma unroll
  for (int i = 0; i < 4; ++i)
#pragma unroll
    for (int j = 0; j < 4; ++j) acc[i][j] = (f32x4){0.f, 0.f, 0.f, 0.f};

  for (int t = 0; t < 6; ++t) {
    int k0 = t * 64;
#pragma unroll
    for (int p = 0; p < 4; ++p) {
      int row = p * 32 + (tid >> 3);
      int seg = (tid & 7) * 8;
      uint4 va = *(const uint4*)(ctx + (gm0 + row) * DIMC + k0 + seg);
      *(uint4*)(As + row * 64 + seg) = va;
      uint4 vb = *(const uint4*)(pwb + (size_t)(gn0 + row) * DIMC + k0 + seg);
      *(uint4*)(Bs + row * 64 + seg) = vb;
    }
    __syncthreads();
#pragma unroll
    for (int kk = 0; kk < 64; kk += 32) {
      short8 a[4], bfr[4];
#pragma unroll
      for (int mi = 0; mi < 4; ++mi)
        a[mi] = *(const short8*)(As + (wr * 64 + mi * 16 + c) * 64 + kk + g * 8);
#pragma unroll
      for (int ni = 0; ni < 4; ++ni)
        bfr[ni] = *(const short8*)(Bs + (wc * 64 + ni * 16 + c) * 64 + kk + g * 8);
#pragma unroll
      for (int mi = 0; mi < 4; ++mi)
#pragma unroll
        for (int ni = 0; ni < 4; ++ni)
          acc[mi][ni] = MFMA(a[mi], bfr[ni], acc[mi][ni]);
    }
    __syncthreads();
  }
#pragma unroll
  for (int mi = 0; mi < 4; ++mi)
#pragma unroll
    for (int ni = 0; ni < 4; ++ni) {
      int gcol = gn0 + wc * 64 + ni * 16 + c;
      float bv = proj_b[gcol];
#pragma unroll
      for (int r = 0; r < 4; ++r) {
        size_t grow = gm0 + wr * 64 + mi * 16 + g * 4 + r;
        out[grow * DIMC + gcol] = acc[mi][ni][r] + bv;
      }
    }
}

extern "C" void kernel_launch(void* const* d_in, const int* in_sizes, int n_in,
                              void* d_out, int out_size, void* d_ws, size_t ws_size,
                              hipStream_t stream) {
  const float* x = (const float*)d_in[0];
  const float* rct = (const float*)d_in[1];
  const int* rpi = (const int*)d_in[2];
  const float* mask = (const float*)d_in[3];
  const float* qkv_w = (const float*)d_in[4];
  const float* q_bias = (const float*)d_in[5];
  const float* k_bias = (const float*)d_in[6];
  const float* v_bias = (const float*)d_in[7];
  const float* logit_scale = (const float*)d_in[8];
  const float* cpb_w1 = (const float*)d_in[9];
  const float* cpb_b1 = (const float*)d_in[10];
  const float* cpb_w2 = (const float*)d_in[11];
  const float* proj_w = (const float*)d_in[12];
  const float* proj_b = (const float*)d_in[13];
  float* out = (float*)d_out;

  char* ws = (char*)d_ws;
  size_t off = 0;
  auto alloc = [&](size_t bytes) {
    void* p = ws + off;
    off = (off + bytes + 255) & ~(size_t)255;
    return p;
  };
  const size_t NX = (size_t)BWIN * NTOK * DIMC;       // 28311552
  u16* xb  = (u16*)alloc(NX * 2);
  u16* wqb = (u16*)alloc((size_t)3 * DIMC * DIMC * 2);
  u16* pwb = (u16*)alloc((size_t)DIMC * DIMC * 2);
  u16* ctx = (u16*)alloc(NX * 2);
  float* cbv = (float*)alloc((size_t)NWIN * NHEADS * NTOK * NTOK * 4);
  float* bias_tab = (float*)alloc((size_t)TABLEN * NHEADS * 4);
  float* scalev = (float*)alloc(64 * 4);

  cvt_bf16<<<(int)(NX / 8 + 255) / 256, 256, 0, stream>>>(x, xb, (int)(NX / 8));
  cvt_bf16<<<(3 * DIMC * DIMC / 8 + 255) / 256, 256, 0, stream>>>(qkv_w, wqb, 3 * DIMC * DIMC / 8);
  cvt_bf16<<<(DIMC * DIMC / 8 + 255) / 256, 256, 0, stream>>>(proj_w, pwb, DIMC * DIMC / 8);
  cpb_kernel<<<(TABLEN * NHEADS + 255) / 256, 256, 0, stream>>>(
      rct, cpb_w1, cpb_b1, cpb_w2, logit_scale, bias_tab, scalev);
  cbias_kernel<<<(NWIN * NHEADS * NTOK * NTOK + 255) / 256, 256, 0, stream>>>(
      rpi, bias_tab, mask, cbv);
  attn_fused<<<BWIN * NHEADS, 192, 0, stream>>>(
      xb, wqb, q_bias, k_bias, v_bias, cbv, scalev, ctx);
  proj_gemm<<<(BWIN * NTOK / 128) * 3, 256, 0, stream>>>(ctx, pwb, proj_b, out);
}